// Round 4
// baseline (237.212 us; speedup 1.0000x reference)
//
#include <hip/hip_runtime.h>

// Problem constants (from the reference)
#define F_      30                 // B*5 + C = 2*5 + 20
#define N_IMG_  16384
#define SS_     49
#define NCELL_  (N_IMG_ * SS_)     // 802816
#define COORD_  5.0f
#define NOOBJ_  0.5f

#define TPB             256
#define CELLS_PER_TILE  256
#define NTILE           (NCELL_ / CELLS_PER_TILE)   // 3136
#define NBLK_P          512                         // persistent: 2 blocks/CU
#define FLT_PER_TILE    (CELLS_PER_TILE * F_)       // 7680 floats = 30 KB/array
#define VEC4_PER_TILE   (FLT_PER_TILE / 4)          // 1920 float4 per array
#define K_SLOTS         15                          // float4 chunk-loads per wave per tile

__device__ __forceinline__ float iou_f(const float* pb, const float* tb) {
    float xA = fmaxf(pb[0] - pb[2] * 0.5f, tb[0] - tb[2] * 0.5f);
    float yA = fmaxf(pb[1] - pb[3] * 0.5f, tb[1] - tb[3] * 0.5f);
    float xB = fminf(pb[0] + pb[2] * 0.5f, tb[0] + tb[2] * 0.5f);
    float yB = fminf(pb[1] + pb[3] * 0.5f, tb[1] + tb[3] * 0.5f);
    float inter = fmaxf(0.f, xB - xA) * fmaxf(0.f, yB - yA);
    float areaA = pb[2] * pb[3];
    float areaB = tb[2] * tb[3];
    return inter / (areaA + areaB - inter);
}

__device__ __forceinline__ void cell_loss(float& l, const float* p, const float* q) {
    // p/q: probs[0..19], conf[20..21], box[22..29]
    float d0 = p[20] - q[20];
    float d1 = p[21] - q[21];
    l += NOOBJ_ * (d0 * d0 + d1 * d1);

    const bool obj = q[20] > 0.f;
    if (obj) {
        float sprob = 0.f;
        #pragma unroll
        for (int f = 0; f < 20; ++f) {
            float d = p[f] - q[f];
            sprob += d * d;
        }
        l += sprob;

        // numpy argmax: first max wins -> strict >
        float i0 = iou_f(p + 22, q + 22);
        float i1 = iou_f(p + 26, q + 26);
        int best = (i1 > i0) ? 1 : 0;

        float dc = p[20 + best] - q[20 + best];
        l += (1.0f - NOOBJ_) * dc * dc;

        const float* pb = p + 22 + 4 * best;
        const float* tb = q + 22 + 4 * best;
        float bx = pb[0] - tb[0];
        float by = pb[1] - tb[1];
        float bw = sqrtf(pb[2]) - sqrtf(tb[2]);
        float bh = sqrtf(pb[3]) - sqrtf(tb[3]);
        l += COORD_ * (bx * bx + by * by + bw * bw + bh * bh);
    }
}

__global__ __launch_bounds__(TPB) void mploss_kernel(
        const float* __restrict__ preds,
        const float* __restrict__ targets,
        float* __restrict__ part) {
    __shared__ alignas(16) float s_p[FLT_PER_TILE];
    __shared__ alignas(16) float s_t[FLT_PER_TILE];
    __shared__ float s_red[TPB / 64];

    const int tid  = threadIdx.x;
    const int lane = tid & 63;
    const int wave = tid >> 6;

    // Wave w stages a contiguous 15 KB slice: waves 0,1 -> preds, waves 2,3 -> targets.
    const float4* g4   = (wave < 2) ? (const float4*)preds : (const float4*)targets;
    float4*       lds4 = (wave < 2) ? (float4*)s_p : (float4*)s_t;
    const int u0 = (wave & 1) * K_SLOTS;   // chunk-slot base within the array

    float4 rv[K_SLOTS];

    int t = blockIdx.x;
    // ---- prologue: stage tile t ----
    {
        const long base = (long)t * VEC4_PER_TILE;
        #pragma unroll
        for (int k = 0; k < K_SLOTS; ++k)
            rv[k] = g4[base + (u0 + k) * 64 + lane];
        #pragma unroll
        for (int k = 0; k < K_SLOTS; ++k)
            lds4[(u0 + k) * 64 + lane] = rv[k];
    }
    __syncthreads();

    float l = 0.f;
    // ---- pipelined main loop: load tile t+512 into regs while computing tile t ----
    while (true) {
        const int  tn        = t + NBLK_P;
        const bool have_next = (tn < NTILE);        // block-uniform
        if (have_next) {
            const long base = (long)tn * VEC4_PER_TILE;
            #pragma unroll
            for (int k = 0; k < K_SLOTS; ++k)
                rv[k] = g4[base + (u0 + k) * 64 + lane];
        }

        cell_loss(l, s_p + tid * F_, s_t + tid * F_);

        if (!have_next) break;
        __syncthreads();                             // all waves done reading LDS
        #pragma unroll
        for (int k = 0; k < K_SLOTS; ++k)            // per-register vmcnt waits here
            lds4[(u0 + k) * 64 + lane] = rv[k];
        __syncthreads();                             // tile tn ready
        t = tn;
    }

    // ---- block reduction -> one uncontended store ----
    #pragma unroll
    for (int off = 32; off > 0; off >>= 1)
        l += __shfl_down(l, off, 64);
    if (lane == 0) s_red[wave] = l;
    __syncthreads();
    if (tid == 0)
        part[blockIdx.x] = s_red[0] + s_red[1] + s_red[2] + s_red[3];
}

__global__ __launch_bounds__(TPB) void reduce_kernel(
        const float* __restrict__ part, float* __restrict__ out) {
    __shared__ float s_red[TPB / 64];
    float v = 0.f;
    for (int i = threadIdx.x; i < NBLK_P; i += TPB) v += part[i];
    #pragma unroll
    for (int off = 32; off > 0; off >>= 1)
        v += __shfl_down(v, off, 64);
    const int wave = threadIdx.x >> 6;
    const int lane = threadIdx.x & 63;
    if (lane == 0) s_red[wave] = v;
    __syncthreads();
    if (threadIdx.x == 0)
        out[0] = (s_red[0] + s_red[1] + s_red[2] + s_red[3]) * (1.0f / (float)N_IMG_);
}

extern "C" void kernel_launch(void* const* d_in, const int* in_sizes, int n_in,
                              void* d_out, int out_size, void* d_ws, size_t ws_size,
                              hipStream_t stream) {
    const float* preds   = (const float*)d_in[0];
    const float* targets = (const float*)d_in[1];
    float* out  = (float*)d_out;
    float* part = (float*)d_ws;    // NBLK_P floats = 2 KB scratch

    mploss_kernel<<<NBLK_P, TPB, 0, stream>>>(preds, targets, part);
    reduce_kernel<<<1, TPB, 0, stream>>>(part, out);
}

// Round 6
// 236.718 us; speedup vs baseline: 1.0021x; 1.0021x over previous
//
#include <hip/hip_runtime.h>

// Problem constants (from the reference)
#define F_      30                 // B*5 + C = 2*5 + 20
#define N_IMG_  16384
#define SS_     49
#define NCELL_  (N_IMG_ * SS_)     // 802816
#define COORD_  5.0f
#define NOOBJ_  0.5f

#define TPB             256
#define CELLS_PER_TILE  256
#define NTILE           (NCELL_ / CELLS_PER_TILE)   // 3136
#define NBLK_P          512                         // persistent: 2 blocks/CU (LDS-limited)
#define FLT_PER_TILE    (CELLS_PER_TILE * F_)       // 7680 floats = 30 KB/array
#define VEC4_PER_TILE   (FLT_PER_TILE / 4)          // 1920 float4 per array
#define K_SLOTS         15                          // float4 chunk-loads per wave per tile

__device__ __forceinline__ float iou_f(const float* pb, const float* tb) {
    float xA = fmaxf(pb[0] - pb[2] * 0.5f, tb[0] - tb[2] * 0.5f);
    float yA = fmaxf(pb[1] - pb[3] * 0.5f, tb[1] - tb[3] * 0.5f);
    float xB = fminf(pb[0] + pb[2] * 0.5f, tb[0] + tb[2] * 0.5f);
    float yB = fminf(pb[1] + pb[3] * 0.5f, tb[1] + tb[3] * 0.5f);
    float inter = fmaxf(0.f, xB - xA) * fmaxf(0.f, yB - yA);
    float areaA = pb[2] * pb[3];
    float areaB = tb[2] * tb[3];
    return inter / (areaA + areaB - inter);
}

__device__ __forceinline__ void cell_loss(float& l, const float* p, const float* q) {
    // p/q: probs[0..19], conf[20..21], box[22..29]
    float d0 = p[20] - q[20];
    float d1 = p[21] - q[21];
    l += NOOBJ_ * (d0 * d0 + d1 * d1);

    const bool obj = q[20] > 0.f;
    if (obj) {
        float sprob = 0.f;
        #pragma unroll
        for (int f = 0; f < 20; ++f) {
            float d = p[f] - q[f];
            sprob += d * d;
        }
        l += sprob;

        // numpy argmax: first max wins -> strict >
        float i0 = iou_f(p + 22, q + 22);
        float i1 = iou_f(p + 26, q + 26);
        int best = (i1 > i0) ? 1 : 0;

        float dc = p[20 + best] - q[20 + best];
        l += (1.0f - NOOBJ_) * dc * dc;

        const float* pb = p + 22 + 4 * best;
        const float* tb = q + 22 + 4 * best;
        float bx = pb[0] - tb[0];
        float by = pb[1] - tb[1];
        float bw = sqrtf(pb[2]) - sqrtf(tb[2]);
        float bh = sqrtf(pb[3]) - sqrtf(tb[3]);
        l += COORD_ * (bx * bx + by * by + bw * bw + bh * bh);
    }
}

// __launch_bounds__(256, 1): 1 wave/EU minimum -> VGPR budget up to ~512, so the
// 15-float4 (60 VGPR) staging array stays in registers. R4's default budget (88)
// spilled it to scratch: WRITE_SIZE 98 KB -> 184 MB, dur 70 -> 104 us. LDS
// (60.5 KB) caps residency at 2 blocks/CU regardless, so the cap costs nothing.
__global__ __launch_bounds__(TPB, 1) void mploss_kernel(
        const float* __restrict__ preds,
        const float* __restrict__ targets,
        float* __restrict__ part) {
    __shared__ alignas(16) float s_p[FLT_PER_TILE];
    __shared__ alignas(16) float s_t[FLT_PER_TILE];
    __shared__ float s_red[TPB / 64];

    const int tid  = threadIdx.x;
    const int lane = tid & 63;
    const int wave = tid >> 6;

    // Wave w stages a contiguous 15 KB slice: waves 0,1 -> preds, waves 2,3 -> targets.
    const float4* g4   = (wave < 2) ? (const float4*)preds : (const float4*)targets;
    float4*       lds4 = (wave < 2) ? (float4*)s_p : (float4*)s_t;
    const int u0 = (wave & 1) * K_SLOTS;   // chunk-slot base within the array

    float4 rv[K_SLOTS];

    int t = blockIdx.x;
    // ---- prologue: stage tile t ----
    {
        const long base = (long)t * VEC4_PER_TILE;
        #pragma unroll
        for (int k = 0; k < K_SLOTS; ++k)
            rv[k] = g4[base + (u0 + k) * 64 + lane];
        #pragma unroll
        for (int k = 0; k < K_SLOTS; ++k)
            lds4[(u0 + k) * 64 + lane] = rv[k];
    }
    __syncthreads();

    float l = 0.f;
    // ---- pipelined main loop: load tile t+512 into regs while computing tile t ----
    while (true) {
        const int  tn        = t + NBLK_P;
        const bool have_next = (tn < NTILE);        // block-uniform
        if (have_next) {
            const long base = (long)tn * VEC4_PER_TILE;
            #pragma unroll
            for (int k = 0; k < K_SLOTS; ++k)
                rv[k] = g4[base + (u0 + k) * 64 + lane];
        }

        cell_loss(l, s_p + tid * F_, s_t + tid * F_);

        if (!have_next) break;
        __syncthreads();                             // all waves done reading LDS
        #pragma unroll
        for (int k = 0; k < K_SLOTS; ++k)            // per-register vmcnt waits here
            lds4[(u0 + k) * 64 + lane] = rv[k];
        __syncthreads();                             // tile tn ready
        t = tn;
    }

    // ---- block reduction -> one uncontended store ----
    #pragma unroll
    for (int off = 32; off > 0; off >>= 1)
        l += __shfl_down(l, off, 64);
    if (lane == 0) s_red[wave] = l;
    __syncthreads();
    if (tid == 0)
        part[blockIdx.x] = s_red[0] + s_red[1] + s_red[2] + s_red[3];
}

__global__ __launch_bounds__(256) void reduce_kernel(
        const float* __restrict__ part, float* __restrict__ out) {
    __shared__ float s_red[4];
    float v = 0.f;
    for (int i = threadIdx.x; i < NBLK_P; i += 256) v += part[i];
    #pragma unroll
    for (int off = 32; off > 0; off >>= 1)
        v += __shfl_down(v, off, 64);
    const int wave = threadIdx.x >> 6;
    const int lane = threadIdx.x & 63;
    if (lane == 0) s_red[wave] = v;
    __syncthreads();
    if (threadIdx.x == 0)
        out[0] = (s_red[0] + s_red[1] + s_red[2] + s_red[3]) * (1.0f / (float)N_IMG_);
}

extern "C" void kernel_launch(void* const* d_in, const int* in_sizes, int n_in,
                              void* d_out, int out_size, void* d_ws, size_t ws_size,
                              hipStream_t stream) {
    const float* preds   = (const float*)d_in[0];
    const float* targets = (const float*)d_in[1];
    float* out  = (float*)d_out;
    float* part = (float*)d_ws;    // NBLK_P floats = 2 KB scratch

    mploss_kernel<<<NBLK_P, TPB, 0, stream>>>(preds, targets, part);
    reduce_kernel<<<1, 256, 0, stream>>>(part, out);
}

// Round 7
// 207.930 us; speedup vs baseline: 1.1408x; 1.1384x over previous
//
#include <hip/hip_runtime.h>

// Problem constants (from the reference)
#define F_      30                  // B*5 + C = 2*5 + 20 floats per cell
#define N_IMG_  16384
#define SS_     49
#define NCELL_  (N_IMG_ * SS_)      // 802816
#define COORD_  5.0f
#define NOOBJ_  0.5f

#define TPB     64                  // ONE wave per block: no __syncthreads anywhere
#define CPT     128                 // cells per tile (2 per lane)
#define TILE_F  (CPT * F_)          // 3840 floats per array per tile
#define TILE_B  (TILE_F * 4)        // 15360 bytes = 15 chunks of (64 lanes x 16 B)
#define NCHUNK  15
#define NT      (NCELL_ / CPT)      // 6272 tiles
#define NB      1280                // persistent: 5 blocks/CU (30 KB LDS each)

typedef const __attribute__((address_space(1))) void g_void;
typedef __attribute__((address_space(3))) void lds_void;

__device__ __forceinline__ float iou_f(const float* pb, const float* tb) {
    float xA = fmaxf(pb[0] - pb[2] * 0.5f, tb[0] - tb[2] * 0.5f);
    float yA = fmaxf(pb[1] - pb[3] * 0.5f, tb[1] - tb[3] * 0.5f);
    float xB = fminf(pb[0] + pb[2] * 0.5f, tb[0] + tb[2] * 0.5f);
    float yB = fminf(pb[1] + pb[3] * 0.5f, tb[1] + tb[3] * 0.5f);
    float inter = fmaxf(0.f, xB - xA) * fmaxf(0.f, yB - yA);
    float areaA = pb[2] * pb[3];
    float areaB = tb[2] * tb[3];
    return inter / (areaA + areaB - inter);
}

__device__ __forceinline__ void cell_loss(float& l, const float* p, const float* q) {
    // p/q: probs[0..19], conf[20..21], box[22..29]
    float d0 = p[20] - q[20];
    float d1 = p[21] - q[21];
    l += NOOBJ_ * (d0 * d0 + d1 * d1);

    const bool obj = q[20] > 0.f;
    if (obj) {
        float sprob = 0.f;
        #pragma unroll
        for (int f = 0; f < 20; ++f) {
            float d = p[f] - q[f];
            sprob += d * d;
        }
        l += sprob;

        // numpy argmax: first max wins -> strict >
        float i0 = iou_f(p + 22, q + 22);
        float i1 = iou_f(p + 26, q + 26);
        int best = (i1 > i0) ? 1 : 0;

        float dc = p[20 + best] - q[20 + best];
        l += (1.0f - NOOBJ_) * dc * dc;

        const float* pb = p + 22 + 4 * best;
        const float* tb = q + 22 + 4 * best;
        float bx = pb[0] - tb[0];
        float by = pb[1] - tb[1];
        float bw = sqrtf(pb[2]) - sqrtf(tb[2]);
        float bh = sqrtf(pb[3]) - sqrtf(tb[3]);
        l += COORD_ * (bx * bx + by * by + bw * bw + bh * bh);
    }
}

__global__ __launch_bounds__(TPB) void mploss_kernel(
        const float* __restrict__ preds,
        const float* __restrict__ targets,
        float* __restrict__ part) {
    // single-buffer tile: [preds | targets], 30720 B -> 5 blocks/CU
    __shared__ alignas(16) float s_buf[2 * TILE_F];
    float* const s_p = s_buf;
    float* const s_t = s_buf + TILE_F;

    const int lane = threadIdx.x;   // one wave per block

    const char* gp0 = (const char*)preds;
    const char* gt0 = (const char*)targets;

    float l = 0.f;

    for (int t = blockIdx.x; t < NT; t += NB) {
        // ---- DMA tile t into LDS: 30 x (64 lanes x 16 B), verified width ----
        {
            const char* gp = gp0 + (size_t)t * TILE_B + lane * 16;
            const char* gt = gt0 + (size_t)t * TILE_B + lane * 16;
            #pragma unroll
            for (int k = 0; k < NCHUNK; ++k) {
                __builtin_amdgcn_global_load_lds(
                    (g_void*)(gp + k * 1024),
                    (lds_void*)((char*)s_p + k * 1024), 16, 0, 0);
                __builtin_amdgcn_global_load_lds(
                    (g_void*)(gt + k * 1024),
                    (lds_void*)((char*)s_t + k * 1024), 16, 0, 0);
            }
        }
        // wait for this tile's DMA (in-order vmcnt); no barrier exists in this kernel
        asm volatile("s_waitcnt vmcnt(0)" ::: "memory");

        // ---- compute this lane's two cells (base 240 B = 16-aligned -> b128 reads)
        cell_loss(l, s_p + (2 * lane)     * F_, s_t + (2 * lane)     * F_);
        cell_loss(l, s_p + (2 * lane + 1) * F_, s_t + (2 * lane + 1) * F_);

        // ensure LDS reads have returned before next tile's DMA overwrites the buffer
        asm volatile("s_waitcnt lgkmcnt(0)" ::: "memory");
    }

    // ---- 64-lane shuffle reduction -> one uncontended store per block ----
    #pragma unroll
    for (int off = 32; off > 0; off >>= 1)
        l += __shfl_down(l, off, 64);
    if (lane == 0)
        part[blockIdx.x] = l;
}

__global__ __launch_bounds__(256) void reduce_kernel(
        const float* __restrict__ part, float* __restrict__ out) {
    __shared__ float s_red[4];
    float v = 0.f;
    for (int i = threadIdx.x; i < NB; i += 256) v += part[i];
    #pragma unroll
    for (int off = 32; off > 0; off >>= 1)
        v += __shfl_down(v, off, 64);
    const int wave = threadIdx.x >> 6;
    const int lane = threadIdx.x & 63;
    if (lane == 0) s_red[wave] = v;
    __syncthreads();
    if (threadIdx.x == 0)
        out[0] = (s_red[0] + s_red[1] + s_red[2] + s_red[3]) * (1.0f / (float)N_IMG_);
}

extern "C" void kernel_launch(void* const* d_in, const int* in_sizes, int n_in,
                              void* d_out, int out_size, void* d_ws, size_t ws_size,
                              hipStream_t stream) {
    const float* preds   = (const float*)d_in[0];
    const float* targets = (const float*)d_in[1];
    float* out  = (float*)d_out;
    float* part = (float*)d_ws;    // NB floats = 5 KB scratch

    mploss_kernel<<<NB, TPB, 0, stream>>>(preds, targets, part);
    reduce_kernel<<<1, 256, 0, stream>>>(part, out);
}